// Round 9
// baseline (266.193 us; speedup 1.0000x reference)
//
#include <hip/hip_runtime.h>

// EMA y_t = w*x_t + (1-w)*y_{t-1}, a = 1-w per-channel constant.
// SINGLE fused kernel. Chunk L=64 per BLOCK of 4 waves (256 thr);
// each wave holds its SUB=16-row subchunk ENTIRELY IN REGISTERS
// (xv[16] float4 = 64 VGPR): phase A scans from regs, phase B re-scans from
// regs -- the second pass over x (133 MB of cache reads) is eliminated, and
// the 16 up-front loads give 16 KiB/wave genuinely in flight (R8 post-mortem:
// VGPR_Count 36-40 proved the old "batch of 8/16" was NOT register-resident;
// effective MLP ~6 loads -> latency-bound at 2.6 TB/s).
//
// Intra-block: per-wave zero-seed aggregates combine via LDS with a^16
// powers (same reassociation class as the chunking itself).
// Cross-block sync (proven recipe, rounds 1-8, UNCHANGED):
//   - spin ONLY on flags (relaxed agent-scope u32); data-spin hung twice.
//   - publish: sc1 u64 stores -> s_waitcnt vmcnt(0) -> flag store.
//   - sentinel 0xFF..F validation backs correctness; flags are a gate.
//   - zero fences / cache-maintenance ops.
// NEW: ticket-based virtual block id (atomicAdd, device scope). Only ~2-3
// blocks/CU are co-resident at this VGPR count; tickets make block order =
// start order, so waiting on lower tickets can never deadlock (no dispatch-
// order assumption, per G16).

#define CHUNK_L 64
#define SUB 16
#define NW 4
#define SENTI64 0xFFFFFFFFFFFFFFFFull

__device__ __forceinline__ float clip01(float v) {
    return fminf(fmaxf(v, 0.0f), 1.0f);
}

__global__ __launch_bounds__(256) void ema_fused(
    const float* __restrict__ x, const float* __restrict__ smooth,
    const float* __restrict__ init, float* __restrict__ out,
    float* __restrict__ chunk_last, unsigned int* __restrict__ flags,
    unsigned int* __restrict__ ticket, int T, int C, int P) {
    __shared__ unsigned int vblk_sh;
    __shared__ float agg_sh[NW][256];    // per-wave zero-seed aggregates
    __shared__ float seed_sh[256];       // block carry-in (after lookback)

    const int tid = threadIdx.x;
    const int wv  = tid >> 6;            // wave 0..3
    const int ln  = tid & 63;
    const int c   = ln << 2;

    if (tid == 0) vblk_sh = atomicAdd(ticket, 1u);
    __syncthreads();
    const int blk = (int)vblk_sh;        // virtual block id = start order
    const int b = blk / P;
    const int p = blk - b * P;

    float4 w4 = *(const float4*)(smooth + c);
    w4.x = clip01(w4.x); w4.y = clip01(w4.y); w4.z = clip01(w4.z); w4.w = clip01(w4.w);
    const float ax = 1.0f - w4.x, ay = 1.0f - w4.y, az = 1.0f - w4.z, aw = 1.0f - w4.w;

    // aS = a^SUB (4 squarings), aL = a^CHUNK_L (6 squarings)
    float aSx = ax, aSy = ay, aSz = az, aSw = aw;
    for (int e = SUB; e > 1; e >>= 1) { aSx *= aSx; aSy *= aSy; aSz *= aSz; aSw *= aSw; }
    float aLx = aSx, aLy = aSy, aLz = aSz, aLw = aSw;
    for (int e = CHUNK_L / SUB; e > 1; e >>= 1) { aLx *= aLx; aLy *= aLy; aLz *= aLz; aLw *= aLw; }

    const int sF4 = C >> 2;
    const size_t base =
        ((size_t)b * T + (size_t)p * CHUNK_L + (size_t)wv * SUB) * C;
    const float4* xp = (const float4*)(x + base) + ln;

    // ---- phase A: load subchunk into REGISTERS, zero-seed scan ----
    float4 xv[SUB];
#pragma unroll
    for (int j = 0; j < SUB; ++j) xv[j] = xp[(size_t)j * sF4];

    float y0 = 0.0f, y1 = 0.0f, y2 = 0.0f, y3 = 0.0f;
#pragma unroll
    for (int j = 0; j < SUB; ++j) {
        y0 = fmaf(ax, y0, w4.x * xv[j].x);
        y1 = fmaf(ay, y1, w4.y * xv[j].y);
        y2 = fmaf(az, y2, w4.z * xv[j].z);
        y3 = fmaf(aw, y3, w4.w * xv[j].w);
    }
    { float4 r; r.x = y0; r.y = y1; r.z = y2; r.w = y3;
      *(float4*)&agg_sh[wv][c] = r; }
    __syncthreads();

    // ---- wave 0: block aggregate publish + lookback; others wait ----
    if (wv == 0) {
        // block aggregate = chain of the 4 wave aggregates with a^SUB
        float4 g = *(const float4*)&agg_sh[0][c];
#pragma unroll
        for (int v = 1; v < NW; ++v) {
            const float4 av = *(const float4*)&agg_sh[v][c];
            g.x = fmaf(aSx, g.x, av.x);
            g.y = fmaf(aSy, g.y, av.y);
            g.z = fmaf(aSz, g.z, av.z);
            g.w = fmaf(aSw, g.w, av.w);
        }
        // publish via relaxed agent-scope (sc1) u64 stores
        {
            union { float f[4]; unsigned long long u[2]; } r;
            r.f[0] = g.x; r.f[1] = g.y; r.f[2] = g.z; r.f[3] = g.w;
            unsigned long long* dst =
                (unsigned long long*)(chunk_last + (size_t)blk * C + c);
            __hip_atomic_store(dst + 0, r.u[0], __ATOMIC_RELAXED, __HIP_MEMORY_SCOPE_AGENT);
            __hip_atomic_store(dst + 1, r.u[1], __ATOMIC_RELAXED, __HIP_MEMORY_SCOPE_AGENT);
        }
        asm volatile("s_waitcnt vmcnt(0)" ::: "memory");
        if (ln == 0) {
            __hip_atomic_store(flags + blk, 1u, __ATOMIC_RELAXED, __HIP_MEMORY_SCOPE_AGENT);
        }

        // carry-in lookback (proven R7/R8 code)
        float4 s = *(const float4*)(init + (size_t)b * C + c);
        if (p > 0) {
            const unsigned int* fl = flags + (size_t)b * P;
            const unsigned long long* cl =
                (const unsigned long long*)(chunk_last + (size_t)b * P * C) + (ln << 1);
            const int sU64 = C >> 1;

            int q = 0;
            for (; q + 8 <= p; q += 8) {
                while (__hip_atomic_load(fl + (q + 7), __ATOMIC_RELAXED,
                                         __HIP_MEMORY_SCOPE_AGENT) == 0u) {
                    __builtin_amdgcn_s_sleep(16);
                }
                union { float f[4]; unsigned long long u[2]; } l[8];
                for (;;) {
                    bool ok = true;
#pragma unroll
                    for (int j = 0; j < 8; ++j) {
                        const unsigned long long* src = cl + (size_t)(q + j) * sU64;
                        l[j].u[0] = __hip_atomic_load(src + 0, __ATOMIC_RELAXED,
                                                      __HIP_MEMORY_SCOPE_AGENT);
                        l[j].u[1] = __hip_atomic_load(src + 1, __ATOMIC_RELAXED,
                                                      __HIP_MEMORY_SCOPE_AGENT);
                        ok &= (l[j].u[0] != SENTI64) & (l[j].u[1] != SENTI64);
                    }
                    if (__all((int)ok)) break;
                    __builtin_amdgcn_s_sleep(2);
                }
#pragma unroll
                for (int j = 0; j < 8; ++j) {
                    s.x = fmaf(aLx, s.x, l[j].f[0]);
                    s.y = fmaf(aLy, s.y, l[j].f[1]);
                    s.z = fmaf(aLz, s.z, l[j].f[2]);
                    s.w = fmaf(aLw, s.w, l[j].f[3]);
                }
            }
            for (; q < p; ++q) {
                while (__hip_atomic_load(fl + q, __ATOMIC_RELAXED,
                                         __HIP_MEMORY_SCOPE_AGENT) == 0u) {
                    __builtin_amdgcn_s_sleep(8);
                }
                union { float f[4]; unsigned long long u[2]; } l;
                const unsigned long long* src = cl + (size_t)q * sU64;
                for (;;) {
                    l.u[0] = __hip_atomic_load(src + 0, __ATOMIC_RELAXED,
                                               __HIP_MEMORY_SCOPE_AGENT);
                    l.u[1] = __hip_atomic_load(src + 1, __ATOMIC_RELAXED,
                                               __HIP_MEMORY_SCOPE_AGENT);
                    if (__all((int)((l.u[0] != SENTI64) & (l.u[1] != SENTI64)))) break;
                    __builtin_amdgcn_s_sleep(2);
                }
                s.x = fmaf(aLx, s.x, l.f[0]);
                s.y = fmaf(aLy, s.y, l.f[1]);
                s.z = fmaf(aLz, s.z, l.f[2]);
                s.w = fmaf(aLw, s.w, l.f[3]);
            }
        }
        *(float4*)&seed_sh[c] = s;
    }
    __syncthreads();

    // ---- per-wave seed: chain block carry-in through preceding waves ----
    float4 sd = *(const float4*)&seed_sh[c];
#pragma unroll
    for (int v = 0; v < NW - 1; ++v) {
        if (v < wv) {
            const float4 av = *(const float4*)&agg_sh[v][c];
            sd.x = fmaf(aSx, sd.x, av.x);
            sd.y = fmaf(aSy, sd.y, av.y);
            sd.z = fmaf(aSz, sd.z, av.z);
            sd.w = fmaf(aSw, sd.w, av.w);
        }
    }

    // ---- phase B: re-scan from REGISTERS, write out ----
    float4* op = (float4*)(out + base) + ln;
    float yb0 = sd.x, yb1 = sd.y, yb2 = sd.z, yb3 = sd.w;
#pragma unroll
    for (int j = 0; j < SUB; ++j) {
        yb0 = fmaf(ax, yb0, w4.x * xv[j].x);
        yb1 = fmaf(ay, yb1, w4.y * xv[j].y);
        yb2 = fmaf(az, yb2, w4.z * xv[j].z);
        yb3 = fmaf(aw, yb3, w4.w * xv[j].w);
        float4 r; r.x = yb0; r.y = yb1; r.z = yb2; r.w = yb3;
        op[(size_t)j * sF4] = r;
    }
}

extern "C" void kernel_launch(void* const* d_in, const int* in_sizes, int n_in,
                              void* d_out, int out_size, void* d_ws, size_t ws_size,
                              hipStream_t stream) {
    const float* x      = (const float*)d_in[0];  // [B, T, C]
    const float* init   = (const float*)d_in[1];  // [B, C]
    const float* smooth = (const float*)d_in[2];  // [C]
    float* out = (float*)d_out;

    const int C  = in_sizes[2];
    const int BC = in_sizes[1];
    const int B  = BC / C;
    const int T  = in_sizes[0] / BC;
    const int P  = T / CHUNK_L;

    float* chunk_last = (float*)d_ws;                               // [B*P, C]
    unsigned int* flags =
        (unsigned int*)((char*)d_ws + (size_t)B * P * C * sizeof(float));  // [B*P]
    unsigned int* ticket = flags + (size_t)B * P;                   // [1]

    // Workspace poisoned each iteration. Byte-pattern hipMemsetAsync only:
    // chunk_last -> 0xFF sentinel; flags+ticket -> 0.
    (void)hipMemsetAsync(chunk_last, 0xFF, (size_t)B * P * C * sizeof(float), stream);
    (void)hipMemsetAsync(flags, 0, ((size_t)B * P + 1) * sizeof(unsigned int), stream);

    ema_fused<<<dim3(B * P), dim3(NW * 64), 0, stream>>>(
        x, smooth, init, out, chunk_last, flags, ticket, T, C, P);
}